// Round 11
// baseline (901.100 us; speedup 1.0000x reference)
//
#include <hip/hip_runtime.h>
#include <stdint.h>

#define B_    16
#define L_    2048
#define DIN_  1024
#define H_    512
#define NCOL_ 3072          // 2 * H * 3
#define M_    (B_ * L_)     // 32768
#define K_    DIN_          // 1024
#define NCHUNK 16
#define CHUNK  128          // L_ / NCHUNK

typedef unsigned short u16;
typedef __bf16 bf16_t;
typedef bf16_t bf16x8 __attribute__((ext_vector_type(8)));
typedef float  f32x4  __attribute__((ext_vector_type(4)));

__device__ __forceinline__ u16 f2bf(float f) {
  union { float f; uint32_t u; } v; v.f = f;
  return (u16)((v.u + 0x7fffu + ((v.u >> 16) & 1u)) >> 16);  // RNE
}
__device__ __forceinline__ float bf2f(u16 b) {
  union { uint32_t u; float f; } v; v.u = ((uint32_t)b) << 16; return v.f;
}
__device__ __forceinline__ u16 f2h(float f) {
  _Float16 h = (_Float16)f; return *(u16*)&h;
}
__device__ __forceinline__ float h2f(u16 b) {
  _Float16 h = *(_Float16*)&b; return (float)h;
}

// ---------------- x f32 -> bf16 ----------------
__global__ void cvt_x_kernel(const float4* __restrict__ x, ushort4* __restrict__ xb) {
  int i = blockIdx.x * blockDim.x + threadIdx.x;   // exact grid, no bounds
  float4 v = x[i];
  ushort4 o;
  o.x = f2bf(v.x); o.y = f2bf(v.y); o.z = f2bf(v.z); o.w = f2bf(v.w);
  xb[i] = o;
}

// ---------------- W (K x N) -> Wt (N' x K) bf16, rows plane-permuted ----------------
// n' = k*1024 + d*512 + h  (so the GEMM N axis is planar: [xtil | f | r])
__global__ void transpose_w_kernel(const float* __restrict__ W, u16* __restrict__ Wt) {
  __shared__ float s[32][33];
  int n0 = blockIdx.x * 32;   // N tile
  int i0 = blockIdx.y * 32;   // K tile
  int tx = threadIdx.x, ty = threadIdx.y;  // (32, 8)
  #pragma unroll
  for (int y = 0; y < 32; y += 8)
    s[ty + y][tx] = W[(uint64_t)(i0 + ty + y) * NCOL_ + n0 + tx];
  __syncthreads();
  #pragma unroll
  for (int y = 0; y < 32; y += 8) {
    int n = n0 + ty + y;
    int kk = n % 3, d = n / 1536, h = (n % 1536) / 3;
    int np = kk * 1024 + d * 512 + h;
    Wt[(uint64_t)np * K_ + i0 + tx] = f2bf(s[tx][ty + y]);
  }
}

// ---------------- 256x256 GEMM, 4 FAT waves (128x128 out each), free-run ----------------
__device__ __forceinline__ void gload_lds16(const void* g, void* lds) {
  __builtin_amdgcn_global_load_lds(
      (const __attribute__((address_space(1))) uint32_t*)g,
      (__attribute__((address_space(3))) uint32_t*)lds, 16, 0, 0);
}

__device__ __forceinline__ bf16x8 lds_rd(const u16* lds, int byteOff) {
  return __builtin_bit_cast(bf16x8, *(const f32x4*)((const char*)lds + byteOff));
}

// R11 rationale: R4-R10 varied schedule, tile, blocks/CU, waves/SIMD -> all
// ~250-267us, MfmaUtil pinned at 35%. Invariant identified: per-wave
// arithmetic intensity vs LDS (42.7 FLOP/B), per-CU LDS 256 KB/tile ~= MFMA
// time -> serialized pipes. Fix: 4 waves x 128x128 output (acc[8][8]=256 regs,
// 1 wave/SIMD, 512-reg budget): 64 FLOP/B (+50%), LDS/tile 256->192 KB,
// A-fragment read duplication 4x->2x. MFMA/SIMD unchanged.
//
// LDS map (bytes), 160 KiB, 1 block/CU:
//   A bufs (2): {0,1} * 32768          -- 256 rows x 64 bf16, 128 B/row; tile t -> buf t&1
//   B bufs (3): 65536 + {0,1,2}*32768  -- 256 rows x 64 bf16;            tile t -> buf t%3
// T2 swizzle per 128-B row: phys granule = logical granule ^ (row&7)
//   (linear gload_lds dest + pre-swizzled GLOBAL source; read byte ^= (rr&7)<<4)
//   0 bank conflicts verified R5-R10.
//
// Schedule = R7 free-run (best measured): per tile issue stageA(t+1) then
// stageB(t+2) (8 loads each per wave), then bF(16 reads) + per-mi aF(2 reads)
// + 16 MFMA, compiler-counted lgkm interleave, ONE raw barrier per tile.
// Boundary vmcnt(8): retires A(t+1)+older; B(t+2)'s 8/wave stay in flight.
// Ledger (per-wave issue order A(t+1) before B(t+2) makes vmcnt counts exact):
//   RAW: A(t),B(t) retired by t-1 boundary wait + barrier. WAR: readers of the
//   buffer being overwritten finished reads before passing barrier t-1. Tail:
//   t=14 stages only A(15), boundary vmcnt(0); t=15 stages nothing.
__global__ __launch_bounds__(256, 1) void gemm_u_kernel(const u16* __restrict__ A,
                                                        const u16* __restrict__ Bt,
                                                        const float* __restrict__ bfp,
                                                        const float* __restrict__ brp,
                                                        u16* __restrict__ xtilP,
                                                        u16* __restrict__ fP,
                                                        u16* __restrict__ rP) {
  __shared__ __align__(16) u16 lds[81920];       // 160 KiB

  // Block->tile mapping (R5, FETCH=221MB verified): XCD-chunked M, bm-fast in XCD.
  const int bid = blockIdx.x;
  const int xcd = bid & 7;
  const int li  = bid >> 3;                     // 0..191 within XCD
  const int bm  = xcd * 16 + (li & 15);
  const int bn  = li >> 4;                      // 0..11
  const int m0 = bm * 256, n0 = bn * 256;

  const int tid  = threadIdx.x;
  const int w    = tid >> 6, lane = tid & 63;   // 4 waves, 1 per SIMD
  const int wrM  = w >> 1, wcN = w & 1;         // 2M x 2N; per-wave out 128x128
  const int rr   = lane & 15, hs = lane >> 4;
  const int swzRd = (rr & 7) << 4;
  const int hsOff = hs * 16;

  // staging: chunk c (1 KiB = 8 rows x 128 B): row = c*8 + (lane>>3), granule = lane&7
  const int rSub = lane >> 3;
  const int sCol = ((lane & 7) ^ (lane >> 3)) * 8;   // pre-swizzled source granule

  f32x4 acc[8][8] = {};

  auto stageA = [&](int bufBase, int kt) {      // 32 chunks over 4 waves = 8 loads/wave
    #pragma unroll
    for (int c = w; c < 32; c += 4)
      gload_lds16(A + (uint64_t)(m0 + c * 8 + rSub) * K_ + kt + sCol,
                  (char*)lds + bufBase + c * 1024);
  };
  auto stageB = [&](int bufBase, int kt) {      // 8 loads/wave
    #pragma unroll
    for (int c = w; c < 32; c += 4)
      gload_lds16(Bt + (uint64_t)(n0 + c * 8 + rSub) * K_ + kt + sCol,
                  (char*)lds + bufBase + c * 1024);
  };

  // prologue: A(0)->Ab0, B(0)->Bb0 (16 oldest), B(1)->Bb1 (8 newest, stay in flight)
  stageA(0, 0);
  stageB(65536, 0);
  stageB(65536 + 32768, 64);
  asm volatile("s_waitcnt vmcnt(8)" ::: "memory");
  __builtin_amdgcn_sched_barrier(0);
  __builtin_amdgcn_s_barrier();

  const int aRow0 = wrM * 128;                  // A rows for this wave
  const int bRow0 = wcN * 128;                  // B rows for this wave

  int b3 = 0;                                    // t % 3
  #pragma unroll 1
  for (int t = 0; t < 16; ++t) {
    const int curA = (t & 1) << 15;
    const int curB = 65536 + b3 * 32768;
    const int b3n2 = (b3 >= 1) ? (b3 - 1) : 2;   // (t+2) % 3

    // issue staging first: A(t+1) (8 loads), then B(t+2) (8 loads, newest)
    if (t < 15) stageA((~t & 1) << 15, (t + 1) * 64);
    if (t < 14) stageB(65536 + b3n2 * 32768, (t + 2) * 64);

    // B fragments for the whole tile (16 reads, 64 VGPR live)
    bf16x8 bF[8][2];
    #pragma unroll
    for (int ni = 0; ni < 8; ++ni)
      #pragma unroll
      for (int ks = 0; ks < 2; ++ks)
        bF[ni][ks] = lds_rd(lds, curB + (bRow0 + ni * 16 + rr) * 128 + ((ks * 64 + hsOff) ^ swzRd));

    // per-mi: 2 aF reads + 16 MFMA (compiler pipelines reads ahead)
    #pragma unroll
    for (int mi = 0; mi < 8; ++mi) {
      bf16x8 aF[2];
      #pragma unroll
      for (int ks = 0; ks < 2; ++ks)
        aF[ks] = lds_rd(lds, curA + (aRow0 + mi * 16 + rr) * 128 + ((ks * 64 + hsOff) ^ swzRd));
      #pragma unroll
      for (int ni = 0; ni < 8; ++ni)
        #pragma unroll
        for (int ks = 0; ks < 2; ++ks)
          acc[mi][ni] = __builtin_amdgcn_mfma_f32_16x16x32_bf16(aF[ks], bF[ni][ks], acc[mi][ni], 0, 0, 0);
    }

    // boundary: A(t+1)+older retired; B(t+2)'s 8 loads stay in flight
    if (t < 14) {
      asm volatile("s_waitcnt vmcnt(8)" ::: "memory");
      __builtin_amdgcn_sched_barrier(0);
    } else if (t == 14) {
      asm volatile("s_waitcnt vmcnt(0)" ::: "memory");
      __builtin_amdgcn_sched_barrier(0);
    }
    if (t < 15) __builtin_amdgcn_s_barrier();

    b3 = (b3 + 1 == 3) ? 0 : b3 + 1;
  }

  // epilogue: C/D col = lane&15, row = (lane>>4)*4 + i  [m89-verified].
  // N planar: 16-col groups never cross 1024 -> plane select uniform per ni.
  #pragma unroll
  for (int ni = 0; ni < 8; ++ni) {
    const int col = n0 + wcN * 128 + ni * 16 + rr;
    const int kk  = col >> 10;                 // 0: xtil, 1: f, 2: r
    const int ch  = col & 1023;
    u16* plane = (kk == 0) ? xtilP : (kk == 1 ? fP : rP);
    const float bias = kk ? ((kk == 1 ? bfp : brp)[ch]) : 0.f;
    #pragma unroll
    for (int mi = 0; mi < 8; ++mi) {
      #pragma unroll
      for (int i = 0; i < 4; ++i) {
        const int row = m0 + wrM * 128 + mi * 16 + hs * 4 + i;
        float v = acc[mi][ni][i];
        if (kk) v = 1.f / (1.f + __expf(-(v + bias)));   // uniform branch
        plane[(uint64_t)row * 1024 + ch] = f2h(v);
      }
    }
  }
}

// ---------------- chunked scan, phase A: per-chunk partial (c0=0) + decay product ----------------
__global__ __launch_bounds__(256) void scan_partial_kernel(const u16* __restrict__ xtilP,
                                                           const u16* __restrict__ fP,
                                                           float* __restrict__ cpart,
                                                           float* __restrict__ Pp) {
  int tid = blockIdx.x * 256 + threadIdx.x;       // 262144 = B * NCHUNK * 1024
  int ch = tid & 1023, chunk = (tid >> 10) & (NCHUNK - 1), b = tid >> 14;
  int d = ch >> 9;
  int l = chunk * CHUNK + (d ? CHUNK - 1 : 0);
  int64_t stride = d ? -1024 : 1024;
  uint64_t base = ((uint64_t)b * L_ + l) * 1024 + ch;
  float c = 0.f, P = 1.f;
  #pragma unroll 4
  for (int it = 0; it < CHUNK; ++it) {
    float f  = h2f(fP[base]);
    float xt = h2f(xtilP[base]);
    c = f * c + (1.f - f) * xt;
    P *= f;
    base += stride;
  }
  int o = (b * NCHUNK + chunk) * 1024 + ch;
  cpart[o] = c;
  Pp[o] = P;
}

// ---------------- phase B: sequential combine across chunks (per channel) ----------------
__global__ void scan_combine_kernel(const float* __restrict__ cpart, const float* __restrict__ Pp,
                                    float* __restrict__ cin, float* __restrict__ outc) {
  int tid = blockIdx.x * blockDim.x + threadIdx.x;  // 16384
  int ch = tid & 1023, b = tid >> 10, d = ch >> 9;
  float c = 0.f;
  for (int i = 0; i < NCHUNK; ++i) {
    int chunk = d ? (NCHUNK - 1 - i) : i;
    int o = (b * NCHUNK + chunk) * 1024 + ch;
    cin[o] = c;
    c = cpart[o] + Pp[o] * c;
  }
  outc[ch * B_ + b] = c;   // c.T layout (2H, B)
}

// ---------------- phase C: re-scan each chunk from true c_in, emit h ----------------
__global__ __launch_bounds__(256) void scan_final_kernel(const u16* __restrict__ xb,
                                                         const u16* __restrict__ xtilP,
                                                         const u16* __restrict__ fP,
                                                         const u16* __restrict__ rP,
                                                         const float* __restrict__ cin,
                                                         float* __restrict__ outh) {
  int tid = blockIdx.x * 256 + threadIdx.x;       // 262144
  int ch = tid & 1023, chunk = (tid >> 10) & (NCHUNK - 1), b = tid >> 14;
  int d = ch >> 9;
  int l = chunk * CHUNK + (d ? CHUNK - 1 : 0);
  int64_t stride = d ? -1024 : 1024;
  uint64_t base = ((uint64_t)b * L_ + l) * 1024 + ch;
  float c = cin[(b * NCHUNK + chunk) * 1024 + ch];
  #pragma unroll 2
  for (int it = 0; it < CHUNK; ++it) {
    float f    = h2f(fP[base]);
    float xt   = h2f(xtilP[base]);
    float rr   = h2f(rP[base]);
    float xres = bf2f(xb[base]);
    c = f * c + (1.f - f) * xt;
    float th = 1.f - 2.f / (__expf(2.f * c) + 1.f);   // tanh
    outh[base] = rr * th + (1.f - rr) * xres;
    base += stride;
  }
}

// ---------------- launch ----------------
extern "C" void kernel_launch(void* const* d_in, const int* in_sizes, int n_in,
                              void* d_out, int out_size, void* d_ws, size_t ws_size,
                              hipStream_t stream) {
  const float* x   = (const float*)d_in[0];
  const float* W   = (const float*)d_in[1];
  const float* bfp = (const float*)d_in[2];
  const float* brp = (const float*)d_in[3];

  float* outh = (float*)d_out;
  float* outc = outh + (size_t)B_ * L_ * DIN_;   // after (B, L, 2H)

  // ws layout (262 MiB total):
  u16* xb = (u16*)d_ws;                          // M_*K_ bf16      = 64 MiB (live: phase-C residual)
  u16* Wt = xb + (size_t)M_ * K_;                // NCOL_*K_ bf16   = 6 MiB (dead after GEMM)
  u16* xtilP = Wt + (size_t)NCOL_ * K_;          // M_*1024 fp16    = 64 MiB
  u16* fP    = xtilP + (size_t)M_ * 1024;        // 64 MiB
  u16* rP    = fP    + (size_t)M_ * 1024;        // 64 MiB
  // chunk-scan scratch aliases the dead Wt region (3 MiB <= 6 MiB):
  float* cpart = (float*)Wt;                     // B*NCHUNK*1024 f32 = 1 MiB
  float* Pp    = cpart + (size_t)B_ * NCHUNK * 1024;
  float* cin   = Pp    + (size_t)B_ * NCHUNK * 1024;

  cvt_x_kernel<<<(M_ * K_ / 4) / 256, 256, 0, stream>>>((const float4*)x, (ushort4*)xb);
  transpose_w_kernel<<<dim3(NCOL_ / 32, K_ / 32), dim3(32, 8), 0, stream>>>(W, Wt);
  gemm_u_kernel<<<(M_ / 256) * (NCOL_ / 256), 256, 0, stream>>>(xb, Wt, bfp, brp, xtilP, fP, rP);
  scan_partial_kernel<<<(B_ * NCHUNK * 1024) / 256, 256, 0, stream>>>(xtilP, fP, cpart, Pp);
  scan_combine_kernel<<<(B_ * 2 * H_) / 256, 256, 0, stream>>>(cpart, Pp, cin, outc);
  scan_final_kernel<<<(B_ * NCHUNK * 1024) / 256, 256, 0, stream>>>(xb, xtilP, fP, rP, cin, outh);
}

// Round 12
// 381.351 us; speedup vs baseline: 2.3629x; 2.3629x over previous
//
#include <hip/hip_runtime.h>
#include <stdint.h>

#define B_    16
#define L_    2048
#define DIN_  1024
#define H_    512
#define NCOL_ 3072          // 2 * H * 3
#define M_    (B_ * L_)     // 32768
#define K_    DIN_          // 1024
#define NCHUNK 16
#define CHUNK  128          // L_ / NCHUNK

typedef unsigned short u16;
typedef __bf16 bf16_t;
typedef bf16_t bf16x8 __attribute__((ext_vector_type(8)));
typedef float  f32x4  __attribute__((ext_vector_type(4)));

__device__ __forceinline__ u16 f2bf(float f) {
  union { float f; uint32_t u; } v; v.f = f;
  return (u16)((v.u + 0x7fffu + ((v.u >> 16) & 1u)) >> 16);  // RNE
}
__device__ __forceinline__ float bf2f(u16 b) {
  union { uint32_t u; float f; } v; v.u = ((uint32_t)b) << 16; return v.f;
}
__device__ __forceinline__ u16 f2h(float f) {
  _Float16 h = (_Float16)f; return *(u16*)&h;
}
__device__ __forceinline__ float h2f(u16 b) {
  _Float16 h = *(_Float16*)&b; return (float)h;
}

// ---------------- x f32 -> bf16 ----------------
__global__ void cvt_x_kernel(const float4* __restrict__ x, ushort4* __restrict__ xb) {
  int i = blockIdx.x * blockDim.x + threadIdx.x;   // exact grid, no bounds
  float4 v = x[i];
  ushort4 o;
  o.x = f2bf(v.x); o.y = f2bf(v.y); o.z = f2bf(v.z); o.w = f2bf(v.w);
  xb[i] = o;
}

// ---------------- W (K x N) -> Wt (N' x K) bf16, rows plane-permuted ----------------
// n' = k*1024 + d*512 + h  (so the GEMM N axis is planar: [xtil | f | r])
__global__ void transpose_w_kernel(const float* __restrict__ W, u16* __restrict__ Wt) {
  __shared__ float s[32][33];
  int n0 = blockIdx.x * 32;   // N tile
  int i0 = blockIdx.y * 32;   // K tile
  int tx = threadIdx.x, ty = threadIdx.y;  // (32, 8)
  #pragma unroll
  for (int y = 0; y < 32; y += 8)
    s[ty + y][tx] = W[(uint64_t)(i0 + ty + y) * NCOL_ + n0 + tx];
  __syncthreads();
  #pragma unroll
  for (int y = 0; y < 32; y += 8) {
    int n = n0 + ty + y;
    int kk = n % 3, d = n / 1536, h = (n % 1536) / 3;
    int np = kk * 1024 + d * 512 + h;
    Wt[(uint64_t)np * K_ + i0 + tx] = f2bf(s[tx][ty + y]);
  }
}

// ---------------- 256x256 GEMM, ONE barrier per K-tile, compiler-scheduled ----------------
__device__ __forceinline__ void gload_lds16(const void* g, void* lds) {
  __builtin_amdgcn_global_load_lds(
      (const __attribute__((address_space(1))) uint32_t*)g,
      (__attribute__((address_space(3))) uint32_t*)lds, 16, 0, 0);
}

__device__ __forceinline__ bf16x8 lds_rd(const u16* lds, int byteOff) {
  return __builtin_bit_cast(bf16x8, *(const f32x4*)((const char*)lds + byteOff));
}

// LDS map (bytes), 160 KiB total:
//   A bufs (2): [0, 32768), [32768, 65536)           -- 256 rows x 64 bf16, 128 B/row
//   B bufs (3): 65536 + {0,1,2} * 32768              -- same shape
// T2 swizzle per 128-B row: phys granule g_p = g_l ^ (row&7)
//   write: linear gload_lds dest + pre-swizzled GLOBAL source granule
//   read:  byte ^= (row&7)<<4  -> conflict-free ds_read_b128 (verified 0 in R5-R10)
//
// R7 schedule (best measured: GEMM 249us / 828 TF): free-running tile, ONE raw
// barrier per K-tile boundary. Per tile t: issue stageA(t+1)/stageB(t+2); read
// bF + per-quadrant aF; MFMAs interleave with reads via compiler-emitted
// counted lgkmcnt (no intra-tile barriers, no lgkmcnt(0) drains, no pinning).
//   Correctness: RAW (buffer t staged before reads) = vmcnt(4)+boundary
//   barrier of t-1; WAR (re-staging buffer read at t-1) = each wave's
//   t-1 reads complete before its last t-1 MFMA issues (compiler lgkm
//   waits), which precedes the boundary barrier; staging issued after.
__global__ __launch_bounds__(512, 2) void gemm_u_kernel(const u16* __restrict__ A,
                                                        const u16* __restrict__ Bt,
                                                        const float* __restrict__ bfp,
                                                        const float* __restrict__ brp,
                                                        u16* __restrict__ xtilP,
                                                        u16* __restrict__ fP,
                                                        u16* __restrict__ rP) {
  __shared__ __align__(16) u16 lds[81920];       // 160 KiB

  // Block->tile mapping (R5): XCD-chunked M (16 bm per XCD), bm-fast within XCD.
  const int bid = blockIdx.x;
  const int xcd = bid & 7;
  const int li  = bid >> 3;                     // 0..191 within XCD
  const int bm  = xcd * 16 + (li & 15);
  const int bn  = li >> 4;                      // 0..11
  const int m0 = bm * 256, n0 = bn * 256;

  const int tid  = threadIdx.x;
  const int w    = tid >> 6, lane = tid & 63;
  const int wr   = w >> 2, wc = w & 3;          // 2M x 4N waves; per-wave out 128x64
  const int rr   = lane & 15, hs = lane >> 4;
  const int swzRd = (rr & 7) << 4;
  const int hsOff = hs * 16;

  // staging: round (h,j), wave w writes LDS [buf + h*16384 + j*8192 + w*1024 + lane*16]
  //  -> row = h*128 + j*64 + w*8 + (lane>>3); granule = lane&7; src granule ^= (row&7)
  const int rStage = w * 8 + (lane >> 3);
  const int sCol   = ((lane & 7) ^ ((lane >> 3) & 7)) * 8;
  const int ldsChunk = w * 1024;

  f32x4 acc[8][4] = {};

  auto stageA = [&](int bufBase, int kt) {
    #pragma unroll
    for (int h = 0; h < 2; ++h)
      #pragma unroll
      for (int j = 0; j < 2; ++j)
        gload_lds16(A + (uint64_t)(m0 + h * 128 + j * 64 + rStage) * K_ + kt + sCol,
                    (char*)lds + bufBase + h * 16384 + j * 8192 + ldsChunk);
  };
  auto stageB = [&](int bufBase, int kt) {
    #pragma unroll
    for (int h = 0; h < 2; ++h)
      #pragma unroll
      for (int j = 0; j < 2; ++j)
        gload_lds16(Bt + (uint64_t)(n0 + h * 128 + j * 64 + rStage) * K_ + kt + sCol,
                    (char*)lds + bufBase + h * 16384 + j * 8192 + ldsChunk);
  };

  // prologue: A(0)->Ab0, B(0)->Bb0, B(1)->Bb1; require A0,B0; leave B1 in flight
  stageA(0, 0);
  stageB(65536, 0);
  stageB(65536 + 32768, 64);
  asm volatile("s_waitcnt vmcnt(4)" ::: "memory");
  __builtin_amdgcn_sched_barrier(0);
  __builtin_amdgcn_s_barrier();

  const int aHalfBase = wr * 16384;             // within A buf
  const int bHalfBase = 65536;                  // (base only; cur buf added per tile)
  const int bQuart    = (wc >> 1) * 16384;      // within B buf
  const int rowB0     = (wc & 1) * 64;

  int b3 = 0;                                    // t % 3
  #pragma unroll 1
  for (int t = 0; t < 16; ++t) {
    const int curA = (t & 1) << 15;
    const int curB = 65536 + b3 * 32768;
    const int b3n2 = (b3 >= 1) ? (b3 - 1) : 2;   // (t+2) % 3

    // issue next-tile staging first (VMEM latency covered by this tile's compute)
    if (t < 15) stageA((~t & 1) << 15, (t + 1) * 64);
    if (t < 14) stageB(65536 + b3n2 * 32768, (t + 2) * 64);

    // B fragments for the whole tile
    bf16x8 bF[4][2];
    #pragma unroll
    for (int ni = 0; ni < 4; ++ni)
      #pragma unroll
      for (int ks = 0; ks < 2; ++ks)
        bF[ni][ks] = lds_rd(lds, curB + bQuart + (rowB0 + ni * 16 + rr) * 128 + ((ks * 64 + hsOff) ^ swzRd));

    // quadrants: reads + MFMAs, compiler-interleaved (counted lgkm waits)
    #pragma unroll
    for (int q = 0; q < 4; ++q) {
      bf16x8 a0[2], a1[2];
      #pragma unroll
      for (int ks = 0; ks < 2; ++ks) {
        a0[ks] = lds_rd(lds, curA + aHalfBase + ((2 * q) * 16 + rr) * 128 + ((ks * 64 + hsOff) ^ swzRd));
        a1[ks] = lds_rd(lds, curA + aHalfBase + ((2 * q + 1) * 16 + rr) * 128 + ((ks * 64 + hsOff) ^ swzRd));
      }
      #pragma unroll
      for (int ni = 0; ni < 4; ++ni)
        #pragma unroll
        for (int ks = 0; ks < 2; ++ks) {
          acc[2 * q][ni]     = __builtin_amdgcn_mfma_f32_16x16x32_bf16(a0[ks], bF[ni][ks], acc[2 * q][ni], 0, 0, 0);
          acc[2 * q + 1][ni] = __builtin_amdgcn_mfma_f32_16x16x32_bf16(a1[ks], bF[ni][ks], acc[2 * q + 1][ni], 0, 0, 0);
        }
    }

    // tile boundary: A(t+1),B(t+1) must be LDS-resident for everyone after the
    // barrier; B(t+2) (4 newest loads) stays in flight across it.
    if (t < 14) {
      asm volatile("s_waitcnt vmcnt(4)" ::: "memory");
      __builtin_amdgcn_sched_barrier(0);
    } else if (t == 14) {
      asm volatile("s_waitcnt vmcnt(0)" ::: "memory");
      __builtin_amdgcn_sched_barrier(0);
    }
    if (t < 15) __builtin_amdgcn_s_barrier();

    b3 = (b3 + 1 == 3) ? 0 : b3 + 1;
  }

  // epilogue: C/D col = lane&15, row = (lane>>4)*4 + i  [m89-verified].
  // N planar: plane kk = n0>>10 block-uniform; ch = (n0&1023) + incol.
  const int kkPlane = n0 >> 10;             // 0: xtil, 1: f, 2: r
  const int chBase  = n0 & 1023;
  u16* plane = (kkPlane == 0) ? xtilP : (kkPlane == 1 ? fP : rP);
  const float* biasp = (kkPlane == 1) ? bfp : brp;
  #pragma unroll
  for (int mi = 0; mi < 8; ++mi) {
    #pragma unroll
    for (int ni = 0; ni < 4; ++ni) {
      const int ch = chBase + wc * 64 + ni * 16 + rr;
      const float bias = kkPlane ? biasp[ch] : 0.f;
      #pragma unroll
      for (int i = 0; i < 4; ++i) {
        const int row = m0 + wr * 128 + mi * 16 + hs * 4 + i;
        float v = acc[mi][ni][i];
        if (kkPlane) v = 1.f / (1.f + __expf(-(v + bias)));   // uniform branch
        plane[(uint64_t)row * 1024 + ch] = f2h(v);
      }
    }
  }
}

// ---------------- chunked scan, phase A: per-chunk partial (c0=0) + decay product ----------------
__global__ __launch_bounds__(256) void scan_partial_kernel(const u16* __restrict__ xtilP,
                                                           const u16* __restrict__ fP,
                                                           float* __restrict__ cpart,
                                                           float* __restrict__ Pp) {
  int tid = blockIdx.x * 256 + threadIdx.x;       // 262144 = B * NCHUNK * 1024
  int ch = tid & 1023, chunk = (tid >> 10) & (NCHUNK - 1), b = tid >> 14;
  int d = ch >> 9;
  int l = chunk * CHUNK + (d ? CHUNK - 1 : 0);
  int64_t stride = d ? -1024 : 1024;
  uint64_t base = ((uint64_t)b * L_ + l) * 1024 + ch;
  float c = 0.f, P = 1.f;
  #pragma unroll 4
  for (int it = 0; it < CHUNK; ++it) {
    float f  = h2f(fP[base]);
    float xt = h2f(xtilP[base]);
    c = f * c + (1.f - f) * xt;
    P *= f;
    base += stride;
  }
  int o = (b * NCHUNK + chunk) * 1024 + ch;
  cpart[o] = c;
  Pp[o] = P;
}

// ---------------- phase B: sequential combine across chunks (per channel) ----------------
__global__ void scan_combine_kernel(const float* __restrict__ cpart, const float* __restrict__ Pp,
                                    float* __restrict__ cin, float* __restrict__ outc) {
  int tid = blockIdx.x * blockDim.x + threadIdx.x;  // 16384
  int ch = tid & 1023, b = tid >> 10, d = ch >> 9;
  float c = 0.f;
  for (int i = 0; i < NCHUNK; ++i) {
    int chunk = d ? (NCHUNK - 1 - i) : i;
    int o = (b * NCHUNK + chunk) * 1024 + ch;
    cin[o] = c;
    c = cpart[o] + Pp[o] * c;
  }
  outc[ch * B_ + b] = c;   // c.T layout (2H, B)
}

// ---------------- phase C: re-scan each chunk from true c_in, emit h ----------------
__global__ __launch_bounds__(256) void scan_final_kernel(const u16* __restrict__ xb,
                                                         const u16* __restrict__ xtilP,
                                                         const u16* __restrict__ fP,
                                                         const u16* __restrict__ rP,
                                                         const float* __restrict__ cin,
                                                         float* __restrict__ outh) {
  int tid = blockIdx.x * 256 + threadIdx.x;       // 262144
  int ch = tid & 1023, chunk = (tid >> 10) & (NCHUNK - 1), b = tid >> 14;
  int d = ch >> 9;
  int l = chunk * CHUNK + (d ? CHUNK - 1 : 0);
  int64_t stride = d ? -1024 : 1024;
  uint64_t base = ((uint64_t)b * L_ + l) * 1024 + ch;
  float c = cin[(b * NCHUNK + chunk) * 1024 + ch];
  #pragma unroll 2
  for (int it = 0; it < CHUNK; ++it) {
    float f    = h2f(fP[base]);
    float xt   = h2f(xtilP[base]);
    float rr   = h2f(rP[base]);
    float xres = bf2f(xb[base]);
    c = f * c + (1.f - f) * xt;
    float th = 1.f - 2.f / (__expf(2.f * c) + 1.f);   // tanh
    outh[base] = rr * th + (1.f - rr) * xres;
    base += stride;
  }
}

// ---------------- launch ----------------
extern "C" void kernel_launch(void* const* d_in, const int* in_sizes, int n_in,
                              void* d_out, int out_size, void* d_ws, size_t ws_size,
                              hipStream_t stream) {
  const float* x   = (const float*)d_in[0];
  const float* W   = (const float*)d_in[1];
  const float* bfp = (const float*)d_in[2];
  const float* brp = (const float*)d_in[3];

  float* outh = (float*)d_out;
  float* outc = outh + (size_t)B_ * L_ * DIN_;   // after (B, L, 2H)

  // ws layout (262 MiB total):
  u16* xb = (u16*)d_ws;                          // M_*K_ bf16      = 64 MiB (live: phase-C residual)
  u16* Wt = xb + (size_t)M_ * K_;                // NCOL_*K_ bf16   = 6 MiB (dead after GEMM)
  u16* xtilP = Wt + (size_t)NCOL_ * K_;          // M_*1024 fp16    = 64 MiB
  u16* fP    = xtilP + (size_t)M_ * 1024;        // 64 MiB
  u16* rP    = fP    + (size_t)M_ * 1024;        // 64 MiB
  // chunk-scan scratch aliases the dead Wt region (3 MiB <= 6 MiB):
  float* cpart = (float*)Wt;                     // B*NCHUNK*1024 f32 = 1 MiB
  float* Pp    = cpart + (size_t)B_ * NCHUNK * 1024;
  float* cin   = Pp    + (size_t)B_ * NCHUNK * 1024;

  cvt_x_kernel<<<(M_ * K_ / 4) / 256, 256, 0, stream>>>((const float4*)x, (ushort4*)xb);
  transpose_w_kernel<<<dim3(NCOL_ / 32, K_ / 32), dim3(32, 8), 0, stream>>>(W, Wt);
  gemm_u_kernel<<<(M_ / 256) * (NCOL_ / 256), 512, 0, stream>>>(xb, Wt, bfp, brp, xtilP, fP, rP);
  scan_partial_kernel<<<(B_ * NCHUNK * 1024) / 256, 256, 0, stream>>>(xtilP, fP, cpart, Pp);
  scan_combine_kernel<<<(B_ * 2 * H_) / 256, 256, 0, stream>>>(cpart, Pp, cin, outc);
  scan_final_kernel<<<(B_ * NCHUNK * 1024) / 256, 256, 0, stream>>>(xb, xtilP, fP, rP, cin, outh);
}